// Round 1
// baseline (608.668 us; speedup 1.0000x reference)
//
#include <hip/hip_runtime.h>
#include <hip/hip_bf16.h>

#define NB 32768
#define NSLOT 64
#define EPS 1e-5f

using bf16 = __hip_bfloat16;

// ---------- storage-type helpers (f32 or bf16 workspace) ----------
template<typename TY> __device__ __forceinline__ float ldF(const TY* p, size_t i);
template<> __device__ __forceinline__ float ldF<float>(const float* p, size_t i){ return p[i]; }
template<> __device__ __forceinline__ float ldF<bf16 >(const bf16*  p, size_t i){ return __bfloat162float(p[i]); }
template<typename TY> __device__ __forceinline__ void stF(TY* p, size_t i, float v);
template<> __device__ __forceinline__ void stF<float>(float* p, size_t i, float v){ p[i] = v; }
template<> __device__ __forceinline__ void stF<bf16 >(bf16*  p, size_t i, float v){ p[i] = __float2bfloat16(v); }

// ---------------- Kernel A: MLP + xcorr + first convs + BN1 stats ----------------
template<typename TY>
__global__ __launch_bounds__(256)
void kA(const float* __restrict__ raw, const float* __restrict__ eegf,
        const float* __restrict__ fgw1, const float* __restrict__ fgb1,
        const float* __restrict__ fgw2, const float* __restrict__ fgb2,
        const float* __restrict__ t1w1, const float* __restrict__ t1b1,
        const float* __restrict__ t2w1, const float* __restrict__ t2b1,
        const float* __restrict__ c0w,  const float* __restrict__ c0b,
        const float* __restrict__ c1w1, const float* __restrict__ c1b1,
        TY* __restrict__ yws, float* __restrict__ stat1)
{
    __shared__ float raw_s[4][756];
    __shared__ float eeg_s[4][684];   // [c][t] = c*57+t
    __shared__ float ec_s[4][513];    // [t][d] = t*9+d
    __shared__ float y_s[3][4][288];  // [o][t] = o*18+t
    __shared__ float h35_s[4][35];
    __shared__ float filt_s[4][7];

    const int tid = threadIdx.x;
    const int s0  = blockIdx.x * 4;

    // phase 1: stage raw
    for (int idx = tid; idx < 4 * 756; idx += 256) {
        int s = idx / 756, i = idx % 756;
        raw_s[s][i] = raw[(size_t)(s0 + s) * 756 + i];
    }
    __syncthreads();

    // phase 2: h35 = tanh(eegf @ fg_w1 + b1)
    if (tid < 140) {
        int s = tid / 35, j = tid % 35;
        const float* e = eegf + (size_t)(s0 + s) * 168;
        float a = fgb1[j];
        for (int i = 0; i < 168; ++i) a = fmaf(e[i], fgw1[i * 35 + j], a);
        h35_s[s][j] = tanhf(a);
    }
    __syncthreads();

    // phase 3: filt = tanh(h35 @ fg_w2 + b2)
    if (tid < 28) {
        int s = tid / 7, k = tid % 7;
        float a = fgb2[k];
        for (int j = 0; j < 35; ++j) a = fmaf(h35_s[s][j], fgw2[j * 7 + k], a);
        filt_s[s][k] = tanhf(a);
    }
    __syncthreads();

    // phase 4: eeg[c][t] = sum_k raw[c*63 + t + k] * filt[k]   (pad never touched)
    for (int idx = tid; idx < 4 * 684; idx += 256) {
        int s = idx / 684, r = idx % 684;
        int c = r / 57, t = r % 57;
        const float* rp = &raw_s[s][c * 63 + t];
        float a = 0.f;
        #pragma unroll
        for (int k = 0; k < 7; ++k) a = fmaf(rp[k], filt_s[s][k], a);
        eeg_s[s][r] = a;
    }
    __syncthreads();

    // phase 5: y1 = conv1d(eeg, t1_w1, stride 3, k=6) + b
    for (int idx = tid; idx < 4 * 288; idx += 256) {
        int s = idx / 288, r = idx % 288;
        int o = r / 18, t = r % 18;
        float a = t1b1[o];
        for (int c = 0; c < 12; ++c) {
            const float* ep = &eeg_s[s][c * 57 + 3 * t];
            const float* wp = &t1w1[o * 72 + c * 6];
            #pragma unroll
            for (int k = 0; k < 6; ++k) a = fmaf(ep[k], wp[k], a);
        }
        y_s[0][s][r] = a;
    }
    // phase 6: y2 = conv1d(eeg, t2_w1, stride 3, k=3, dil=2) + b   (indep of phase 5)
    for (int idx = tid; idx < 4 * 288; idx += 256) {
        int s = idx / 288, r = idx % 288;
        int o = r / 18, t = r % 18;
        float a = t2b1[o];
        for (int c = 0; c < 12; ++c) {
            const float* ep = &eeg_s[s][c * 57 + 3 * t];
            const float* wp = &t2w1[o * 36 + c * 3];
            #pragma unroll
            for (int k = 0; k < 3; ++k) a = fmaf(ep[2 * k], wp[k], a);
        }
        y_s[1][s][r] = a;
    }
    // phase 7: ec[t][d] = relu(sum_c eeg[c][t]*c0_w[c][d] + c0_b[d])
    for (int idx = tid; idx < 4 * 513; idx += 256) {
        int s = idx / 513, r = idx % 513;
        int t = r / 9, d = r % 9;
        float a = c0b[d];
        for (int c = 0; c < 12; ++c) a = fmaf(eeg_s[s][c * 57 + t], c0w[c * 9 + d], a);
        ec_s[s][r] = fmaxf(a, 0.f);
    }
    __syncthreads();

    // phase 8: y3 = conv2d(ec, c1_w1, stride (3,1)) + b  -> [16][18]
    for (int idx = tid; idx < 4 * 288; idx += 256) {
        int s = idx / 288, r = idx % 288;
        int o = r / 18, t = r % 18;
        float a = c1b1[o];
        #pragma unroll
        for (int kh = 0; kh < 5; ++kh) {
            const float* ep = &ec_s[s][(3 * t + kh) * 9];
            const float* wp = &c1w1[o * 45 + kh * 9];
            #pragma unroll
            for (int kw = 0; kw < 9; ++kw) a = fmaf(ep[kw], wp[kw], a);
        }
        y_s[2][s][r] = a;
    }
    __syncthreads();

    // phase 9: block-level BN1 partial stats -> slotted atomics
    if (tid < 96) {
        int tau = tid / 32, rem = tid % 32, o = rem >> 1, st = rem & 1;
        float acc = 0.f;
        for (int s = 0; s < 4; ++s)
            for (int t = 0; t < 18; ++t) {
                float v = y_s[tau][s][o * 18 + t];
                acc += st ? v * v : v;
            }
        atomicAdd(&stat1[(blockIdx.x & (NSLOT - 1)) * 96 + tid], acc);
    }
    // phase 10: write y (pre-BN) to workspace
    for (int idx = tid; idx < 3 * 4 * 288; idx += 256) {
        int tau = idx / 1152, rem = idx % 1152, s = rem / 288, r = rem % 288;
        stF<TY>(yws, (size_t)tau * NB * 288 + (size_t)(s0 + s) * 288 + r, y_s[tau][s][r]);
    }
}

// ---------------- BN finalize (stage 1 or 2) ----------------
__global__ void kBN(const float* __restrict__ statp,
                    const float* __restrict__ g0, const float* __restrict__ be0,
                    const float* __restrict__ g1, const float* __restrict__ be1,
                    const float* __restrict__ g2, const float* __restrict__ be2,
                    float nInv, float* __restrict__ bnp)
{
    int tid = threadIdx.x;
    if (tid >= 48) return;
    int tau = tid / 16, o = tid % 16;
    float sum = 0.f, sq = 0.f;
    for (int sl = 0; sl < NSLOT; ++sl) {
        sum += statp[sl * 96 + tid * 2];
        sq  += statp[sl * 96 + tid * 2 + 1];
    }
    float mean = sum * nInv;
    float var  = sq * nInv - mean * mean;
    const float* g  = (tau == 0) ? g0 : (tau == 1) ? g1 : g2;
    const float* be = (tau == 0) ? be0 : (tau == 1) ? be1 : be2;
    float scale = g[o] / sqrtf(var + EPS);
    float shift = be[o] - mean * scale;
    bnp[tid * 2]     = scale;
    bnp[tid * 2 + 1] = shift;
}

// ---------------- Kernel C: BN1+relu, second convs, BN2 stats ----------------
template<typename TY>
__global__ __launch_bounds__(256)
void kC(const TY* __restrict__ yws, const float* __restrict__ bn1,
        const float* __restrict__ t1w2, const float* __restrict__ t1b2,
        const float* __restrict__ t2w2, const float* __restrict__ t2b2,
        const float* __restrict__ c1w2, const float* __restrict__ c1b2,
        TY* __restrict__ zws, float* __restrict__ stat2)
{
    __shared__ float h_s[3][4][288];
    __shared__ float z_s[3][4][80];
    __shared__ float bnp[96];
    const int tid = threadIdx.x;
    const int s0  = blockIdx.x * 4;

    if (tid < 96) bnp[tid] = bn1[tid];
    __syncthreads();

    for (int idx = tid; idx < 3456; idx += 256) {
        int tau = idx / 1152, rem = idx % 1152, s = rem / 288, r = rem % 288, o = r / 18;
        float v = ldF<TY>(yws, (size_t)tau * NB * 288 + (size_t)(s0 + s) * 288 + r);
        h_s[tau][s][r] = fmaxf(fmaf(v, bnp[(tau * 16 + o) * 2], bnp[(tau * 16 + o) * 2 + 1]), 0.f);
    }
    __syncthreads();

    for (int idx = tid; idx < 960; idx += 256) {
        int tau = idx / 320, rem = idx % 320, s = rem / 80, r = rem % 80;
        int o = r / 5, t = r % 5;
        float a;
        if (tau == 0) {
            a = t1b2[o];
            for (int c = 0; c < 16; ++c) {
                const float* hp = &h_s[0][s][c * 18 + 3 * t];
                const float* wp = &t1w2[o * 96 + c * 6];
                #pragma unroll
                for (int k = 0; k < 6; ++k) a = fmaf(hp[k], wp[k], a);
            }
        } else if (tau == 1) {
            a = t2b2[o];
            for (int c = 0; c < 16; ++c) {
                const float* hp = &h_s[1][s][c * 18 + 3 * t];
                const float* wp = &t2w2[o * 48 + c * 3];
                #pragma unroll
                for (int k = 0; k < 3; ++k) a = fmaf(hp[2 * k], wp[k], a);
            }
        } else {
            a = c1b2[o];
            for (int c = 0; c < 16; ++c) {
                const float* hp = &h_s[2][s][c * 18 + 3 * t];
                const float* wp = &c1w2[o * 80 + c * 5];
                #pragma unroll
                for (int k = 0; k < 5; ++k) a = fmaf(hp[k], wp[k], a);
            }
        }
        z_s[tau][s][r] = a;
    }
    __syncthreads();

    if (tid < 96) {
        int tau = tid / 32, rem = tid % 32, o = rem >> 1, st = rem & 1;
        float acc = 0.f;
        for (int s = 0; s < 4; ++s)
            for (int t = 0; t < 5; ++t) {
                float v = z_s[tau][s][o * 5 + t];
                acc += st ? v * v : v;
            }
        atomicAdd(&stat2[(blockIdx.x & (NSLOT - 1)) * 96 + tid], acc);
    }
    for (int idx = tid; idx < 960; idx += 256) {
        int tau = idx / 320, rem = idx % 320, s = rem / 80, r = rem % 80;
        stF<TY>(zws, (size_t)tau * NB * 80 + (size_t)(s0 + s) * 80 + r, z_s[tau][s][r]);
    }
}

// ---------------- Kernel E: BN2+relu, feats, FC, tanh ----------------
template<typename TY>
__global__ __launch_bounds__(256)
void kE(const TY* __restrict__ zws, const float* __restrict__ bn2,
        const float* __restrict__ fcw, const float* __restrict__ fcb,
        float* __restrict__ out)
{
    __shared__ float fcw_s[160 * 50];   // half of fc_w at a time (32 KB)
    __shared__ float feats[8][320];
    __shared__ float fcb_s[50];
    __shared__ float bnp[96];
    const int tid = threadIdx.x;
    const int s0  = blockIdx.x * 8;

    for (int idx = tid; idx < 8000; idx += 256) fcw_s[idx] = fcw[idx];
    if (tid < 50) fcb_s[tid] = fcb[tid];
    if (tid >= 64 && tid < 160) bnp[tid - 64] = bn2[tid - 64];
    __syncthreads();

    // feats: [t1(80) | t2(80) | c1(80) | c1(80)]  (source bug preserved)
    for (int idx = tid; idx < 8 * 320; idx += 256) {
        int s = idx / 320, f = idx % 320;
        int g = f / 80; int tau = (g == 3) ? 2 : g;
        int r = f % 80, o = r / 5;
        float v = ldF<TY>(zws, (size_t)tau * NB * 80 + (size_t)(s0 + s) * 80 + r);
        feats[s][f] = fmaxf(fmaf(v, bnp[(tau * 16 + o) * 2], bnp[(tau * 16 + o) * 2 + 1]), 0.f);
    }
    __syncthreads();

    // FC over f = 0..159
    float accA = 0.f, accB = 0.f;
    int sA = tid / 50, uA = tid % 50;
    int iB = tid + 256, sB = iB / 50, uB = iB % 50;
    if (tid < 400) {
        accA = fcb_s[uA];
        for (int f = 0; f < 160; ++f) accA = fmaf(feats[sA][f], fcw_s[f * 50 + uA], accA);
    }
    if (tid < 144) {
        accB = fcb_s[uB];
        for (int f = 0; f < 160; ++f) accB = fmaf(feats[sB][f], fcw_s[f * 50 + uB], accB);
    }
    __syncthreads();
    // load second half of fc_w
    for (int idx = tid; idx < 8000; idx += 256) fcw_s[idx] = fcw[8000 + idx];
    __syncthreads();
    if (tid < 400) {
        for (int f = 0; f < 160; ++f) accA = fmaf(feats[sA][160 + f], fcw_s[f * 50 + uA], accA);
        out[(size_t)(s0 + sA) * 50 + uA] = tanhf(accA);
    }
    if (tid < 144) {
        for (int f = 0; f < 160; ++f) accB = fmaf(feats[sB][160 + f], fcw_s[f * 50 + uB], accB);
        out[(size_t)(s0 + sB) * 50 + uB] = tanhf(accB);
    }
}

// ---------------- host launcher ----------------
template<typename TY>
static void launch_all(void* const* d_in, void* d_out, void* d_ws, hipStream_t stream)
{
    const float* raw  = (const float*)d_in[0];
    const float* eegf = (const float*)d_in[1];
    const float* fgw1 = (const float*)d_in[2];
    const float* fgb1 = (const float*)d_in[3];
    const float* fgw2 = (const float*)d_in[4];
    const float* fgb2 = (const float*)d_in[5];
    const float* t1w1 = (const float*)d_in[6];
    const float* t1b1 = (const float*)d_in[7];
    const float* t1g1 = (const float*)d_in[8];
    const float* t1be1= (const float*)d_in[9];
    const float* t1w2 = (const float*)d_in[10];
    const float* t1b2 = (const float*)d_in[11];
    const float* t1g2 = (const float*)d_in[12];
    const float* t1be2= (const float*)d_in[13];
    const float* t2w1 = (const float*)d_in[14];
    const float* t2b1 = (const float*)d_in[15];
    const float* t2g1 = (const float*)d_in[16];
    const float* t2be1= (const float*)d_in[17];
    const float* t2w2 = (const float*)d_in[18];
    const float* t2b2 = (const float*)d_in[19];
    const float* t2g2 = (const float*)d_in[20];
    const float* t2be2= (const float*)d_in[21];
    const float* c0w  = (const float*)d_in[22];
    const float* c0b  = (const float*)d_in[23];
    const float* c1w1 = (const float*)d_in[24];
    const float* c1b1 = (const float*)d_in[25];
    const float* c1g1 = (const float*)d_in[26];
    const float* c1be1= (const float*)d_in[27];
    const float* c1w2 = (const float*)d_in[28];
    const float* c1b2 = (const float*)d_in[29];
    const float* c1g2 = (const float*)d_in[30];
    const float* c1be2= (const float*)d_in[31];
    const float* fcw  = (const float*)d_in[32];
    const float* fcb  = (const float*)d_in[33];

    char* ws = (char*)d_ws;
    TY* yws = (TY*)ws;
    TY* zws = (TY*)(ws + (size_t)3 * NB * 288 * sizeof(TY));
    float* stat1 = (float*)(ws + (size_t)3 * NB * 288 * sizeof(TY) + (size_t)3 * NB * 80 * sizeof(TY));
    float* stat2 = stat1 + NSLOT * 96;
    float* bn1   = stat2 + NSLOT * 96;
    float* bn2   = bn1 + 96;

    hipMemsetAsync(stat1, 0, 2 * NSLOT * 96 * sizeof(float), stream);

    kA<TY><<<NB / 4, 256, 0, stream>>>(raw, eegf, fgw1, fgb1, fgw2, fgb2,
                                       t1w1, t1b1, t2w1, t2b1, c0w, c0b, c1w1, c1b1,
                                       yws, stat1);
    kBN<<<1, 64, 0, stream>>>(stat1, t1g1, t1be1, t2g1, t2be1, c1g1, c1be1,
                              1.f / (float)(NB * 18), bn1);
    kC<TY><<<NB / 4, 256, 0, stream>>>(yws, bn1, t1w2, t1b2, t2w2, t2b2, c1w2, c1b2,
                                       zws, stat2);
    kBN<<<1, 64, 0, stream>>>(stat2, t1g2, t1be2, t2g2, t2be2, c1g2, c1be2,
                              1.f / (float)(NB * 5), bn2);
    kE<TY><<<NB / 8, 256, 0, stream>>>(zws, bn2, fcw, fcb, (float*)d_out);
}

extern "C" void kernel_launch(void* const* d_in, const int* in_sizes, int n_in,
                              void* d_out, int out_size, void* d_ws, size_t ws_size,
                              hipStream_t stream)
{
    (void)in_sizes; (void)n_in; (void)out_size;
    size_t statBytes = (2 * NSLOT * 96 + 192) * sizeof(float);
    size_t needF32 = ((size_t)3 * NB * 288 + (size_t)3 * NB * 80) * 4 + statBytes;
    if (ws_size >= needF32)
        launch_all<float>(d_in, d_out, d_ws, stream);
    else
        launch_all<bf16>(d_in, d_out, d_ws, stream);
}